// Round 1
// baseline (161.905 us; speedup 1.0000x reference)
//
#include <hip/hip_runtime.h>
#include <math.h>

// PillarFeatureNet fused: augment(9) -> linear(9x64) -> BN(train, global stats)
// -> ReLU -> max over P.
//
// Key algebra:
//  h[m,p,o] = sum_c f[m,p,c] * W[c,o]
//  f = [x,y,z,r, x-mx, y-my, z-mz, x-px, y-py]
//  => h = x*(W0+W4+W7) + y*(W1+W5+W8) + z*(W2+W6) + r*W3
//         - (mx*W4 + my*W5 + mz*W6 + px*W7 + py*W8)
//  BN stats: mean_o = mu_f . W[:,o];  E[h^2]_o = W[:,o]^T Q W[:,o] / N
//  with mu_f = 9-vector mean, Q = 9x9 second moment of features.
//  Output: out_o = relu(max_p (s_o*h + b_o))  (relu/max commute; fold s into
//  the weights so only a running max is needed).

#define PP 32
#define OUTC 64
#define GRID1 256
#define BLOCK1 256
#define GRID2 2048
#define BLOCK2 256

__device__ __forceinline__ float fVX() { return 0.2f; }

static constexpr float VX = 0.2f, VY = 0.2f;
static constexpr float X0 = -51.2f, Y0 = -51.2f;
static constexpr float BNEPS = 1e-3f;

// ---------------------------------------------------------------------------
// Pass 1: per-pillar features -> accumulate 9 sums + 45 upper-tri products.
// 32 threads (half-wave) per pillar, one thread per point. Per-block partials
// written to ws (no atomics, deterministic). Also caches per-pillar xyz mean.
// ---------------------------------------------------------------------------
__global__ __launch_bounds__(BLOCK1) void pfn_stats_kernel(
    const float* __restrict__ voxels, const int* __restrict__ coords,
    const int* __restrict__ npoints, float* __restrict__ partials,
    float* __restrict__ means, int M)
{
    const int tid  = threadIdx.x;
    const int lane = tid & 63;
    const int sub  = tid & 31;                       // point index within pillar
    const int grp0 = blockIdx.x * (BLOCK1 / 32) + (tid >> 5);
    const int gstr = gridDim.x * (BLOCK1 / 32);

    float acc[54];
#pragma unroll
    for (int k = 0; k < 54; ++k) acc[k] = 0.f;

    for (int m = grp0; m < M; m += gstr) {
        const float4 v = reinterpret_cast<const float4*>(voxels)[m * PP + sub];

        // pillar xyz sums over the 32 points (xor-shuffle within half-wave)
        float sx = v.x, sy = v.y, sz = v.z;
#pragma unroll
        for (int w = 16; w >= 1; w >>= 1) {
            sx += __shfl_xor(sx, w);
            sy += __shfl_xor(sy, w);
            sz += __shfl_xor(sz, w);
        }
        int np = npoints[m]; if (np < 1) np = 1;
        const float inv = 1.f / (float)np;
        const float mx = sx * inv, my = sy * inv, mz = sz * inv;
        if (sub == 0) {
            means[3 * m + 0] = mx;
            means[3 * m + 1] = my;
            means[3 * m + 2] = mz;
        }
        const float px = (float)coords[4 * m + 3] * VX + X0;
        const float py = (float)coords[4 * m + 2] * VY + Y0;

        float f[9];
        f[0] = v.x; f[1] = v.y; f[2] = v.z; f[3] = v.w;
        f[4] = v.x - mx; f[5] = v.y - my; f[6] = v.z - mz;
        f[7] = v.x - px; f[8] = v.y - py;

#pragma unroll
        for (int i = 0; i < 9; ++i) acc[i] += f[i];
        int k = 9;
#pragma unroll
        for (int i = 0; i < 9; ++i) {
#pragma unroll
            for (int j = i; j < 9; ++j) acc[k++] += f[i] * f[j];
        }
    }

    // full-wave reduce (both half-wave pillars contribute to global stats)
#pragma unroll
    for (int k = 0; k < 54; ++k) {
        float a = acc[k];
#pragma unroll
        for (int w = 32; w >= 1; w >>= 1) a += __shfl_xor(a, w);
        acc[k] = a;
    }

    __shared__ float red[BLOCK1 / 64][54];
    if (lane == 0) {
#pragma unroll
        for (int k = 0; k < 54; ++k) red[tid >> 6][k] = acc[k];
    }
    __syncthreads();
    if (tid < 54) {
        float t = 0.f;
#pragma unroll
        for (int w = 0; w < BLOCK1 / 64; ++w) t += red[w][tid];
        partials[blockIdx.x * 64 + tid] = t;
    }
}

// ---------------------------------------------------------------------------
// Finalize: reduce per-block partials, compute per-channel scale/bias.
// ---------------------------------------------------------------------------
__global__ __launch_bounds__(64) void pfn_finalize_kernel(
    const float* __restrict__ partials, const float* __restrict__ W,
    const float* __restrict__ gamma, const float* __restrict__ beta,
    float* __restrict__ sb, float invN)
{
    const int t = threadIdx.x;
    __shared__ float tot[64];
    float s = 0.f;
    for (int b = 0; b < GRID1; ++b) s += partials[b * 64 + t];
    tot[t] = s;
    __syncthreads();

    float w[9];
#pragma unroll
    for (int c = 0; c < 9; ++c) w[c] = W[c * OUTC + t];

    float mean = 0.f;
#pragma unroll
    for (int c = 0; c < 9; ++c) mean += (tot[c] * invN) * w[c];

    float ex2 = 0.f;
    int k = 9;
#pragma unroll
    for (int i = 0; i < 9; ++i) {
#pragma unroll
        for (int j = i; j < 9; ++j) {
            const float q = tot[k++] * invN;
            ex2 += ((i == j) ? 1.f : 2.f) * q * w[i] * w[j];
        }
    }
    const float var = ex2 - mean * mean;
    const float sc  = gamma[t] * rsqrtf(var + BNEPS);
    const float bi  = beta[t] - mean * sc;
    sb[t] = sc;
    sb[64 + t] = bi;
}

// ---------------------------------------------------------------------------
// Pass 2: one wave per pillar, lane = output channel. Per point: 4 FMA + max.
// ---------------------------------------------------------------------------
__global__ __launch_bounds__(BLOCK2) void pfn_out_kernel(
    const float* __restrict__ voxels, const int* __restrict__ coords,
    const float* __restrict__ means, const float* __restrict__ sb,
    const float* __restrict__ W, float* __restrict__ out, int M)
{
    const int o   = threadIdx.x & 63;
    const int wid = threadIdx.x >> 6;

    const float s = sb[o];
    const float b = sb[64 + o];
    float w[9];
#pragma unroll
    for (int c = 0; c < 9; ++c) w[c] = W[c * OUTC + o];

    const float As = s * (w[0] + w[4] + w[7]);
    const float Bs = s * (w[1] + w[5] + w[8]);
    const float Cs = s * (w[2] + w[6]);
    const float Ds = s * w[3];
    const float s4 = s * w[4], s5 = s * w[5], s6 = s * w[6];
    const float s7 = s * w[7], s8 = s * w[8];

    for (int m = blockIdx.x * (BLOCK2 / 64) + wid; m < M;
         m += gridDim.x * (BLOCK2 / 64)) {
        const float mx = means[3 * m + 0];
        const float my = means[3 * m + 1];
        const float mz = means[3 * m + 2];
        const float px = (float)coords[4 * m + 3] * VX + X0;
        const float py = (float)coords[4 * m + 2] * VY + Y0;
        const float E = b - (mx * s4 + my * s5 + mz * s6 + px * s7 + py * s8);

        const float4* vp = reinterpret_cast<const float4*>(voxels) + m * PP;
        float g = -INFINITY;
#pragma unroll 8
        for (int p = 0; p < PP; ++p) {
            const float4 v = vp[p];
            float h = v.x * As;
            h = fmaf(v.y, Bs, h);
            h = fmaf(v.z, Cs, h);
            h = fmaf(v.w, Ds, h);
            g = fmaxf(g, h);
        }
        out[m * OUTC + o] = fmaxf(g + E, 0.f);
    }
}

// ---------------------------------------------------------------------------
extern "C" void kernel_launch(void* const* d_in, const int* in_sizes, int n_in,
                              void* d_out, int out_size, void* d_ws, size_t ws_size,
                              hipStream_t stream)
{
    const float* voxels = (const float*)d_in[0];
    const int*   coords = (const int*)d_in[1];
    const int*   npts   = (const int*)d_in[2];
    const float* W      = (const float*)d_in[3];
    const float* gamma  = (const float*)d_in[4];
    const float* beta   = (const float*)d_in[5];
    float*       out    = (float*)d_out;

    const int M = in_sizes[0] / (PP * 4);   // voxels is (M, P, 4)

    // ws layout (floats): partials[GRID1*64] | scale+bias[128] | means[3*M]
    float* ws       = (float*)d_ws;
    float* partials = ws;
    float* sb       = ws + GRID1 * 64;
    float* means    = sb + 128;

    pfn_stats_kernel<<<GRID1, BLOCK1, 0, stream>>>(voxels, coords, npts,
                                                   partials, means, M);
    pfn_finalize_kernel<<<1, 64, 0, stream>>>(partials, W, gamma, beta, sb,
                                              1.f / (float)(M * PP));
    pfn_out_kernel<<<GRID2, BLOCK2, 0, stream>>>(voxels, coords, means, sb, W,
                                                 out, M);
}

// Round 3
// 126.683 us; speedup vs baseline: 1.2780x; 1.2780x over previous
//
#include <hip/hip_runtime.h>
#include <math.h>

// PillarFeatureNet fused: augment(9) -> linear(9x64) -> BN(train, global
// stats) -> ReLU -> max over P.
//
//  h = x*(W0+W4+W7) + y*(W1+W5+W8) + z*(W2+W6) + r*W3
//      - (mx*W4 + my*W5 + mz*W6 + px*W7 + py*W8)
//  BN stats from 9-vec first moments + 9x9 second moments of features.
//  out_o = relu(max_p (s_o*h + b_o))   (relu/max commute, s folded into W).

#define PP   32
#define OUTC 64
#define G1   512     // stats grid
#define B1   256
#define PPB  32      // pillars per block in out kernel
#define CH   8       // pillars per LDS chunk

static constexpr float VX = 0.2f, VY = 0.2f;
static constexpr float X0 = -51.2f, Y0 = -51.2f;
static constexpr float BNEPS = 1e-3f;

// ---------------------------------------------------------------------------
// Pass 1: lane=point (32 lanes per pillar), depth-1 software prefetch.
// Accumulates 9 first + 45 second feature moments per lane; block tree-reduce;
// partials stored transposed [54][G1]. Also writes per-pillar xyz mean (float4).
// ---------------------------------------------------------------------------
__global__ __launch_bounds__(B1) void pfn_stats(
    const float4* __restrict__ vox, const int4* __restrict__ coords,
    const int* __restrict__ npts, float* __restrict__ partials,
    float4* __restrict__ means, int M)
{
    const int tid  = threadIdx.x;
    const int sub  = tid & 31;
    const int grp  = blockIdx.x * (B1 / 32) + (tid >> 5);
    const int gstr = G1 * (B1 / 32);

    float acc[54];
#pragma unroll
    for (int k = 0; k < 54; ++k) acc[k] = 0.f;

    int m = grp;
    float4 v = make_float4(0.f, 0.f, 0.f, 0.f);
    int np = 1;
    int4 cd = make_int4(0, 0, 0, 0);
    if (m < M) { v = vox[m * PP + sub]; np = npts[m]; cd = coords[m]; }

    while (m < M) {
        const int mn = m + gstr;
        float4 vn = make_float4(0.f, 0.f, 0.f, 0.f);
        int npn = 1;
        int4 cdn = make_int4(0, 0, 0, 0);
        if (mn < M) { vn = vox[mn * PP + sub]; npn = npts[mn]; cdn = coords[mn]; }

        // pillar xyz sums over 32 points (xor masks <=16 stay in the half-wave)
        float sx = v.x, sy = v.y, sz = v.z;
#pragma unroll
        for (int w = 16; w >= 1; w >>= 1) {
            sx += __shfl_xor(sx, w);
            sy += __shfl_xor(sy, w);
            sz += __shfl_xor(sz, w);
        }
        if (np < 1) np = 1;
        const float inv = 1.f / (float)np;
        const float mx = sx * inv, my = sy * inv, mz = sz * inv;
        if (sub == 0) means[m] = make_float4(mx, my, mz, 0.f);
        const float px = (float)cd.w * VX + X0;
        const float py = (float)cd.z * VY + Y0;

        float f[9];
        f[0] = v.x; f[1] = v.y; f[2] = v.z; f[3] = v.w;
        f[4] = v.x - mx; f[5] = v.y - my; f[6] = v.z - mz;
        f[7] = v.x - px; f[8] = v.y - py;

#pragma unroll
        for (int i = 0; i < 9; ++i) acc[i] += f[i];
        int k = 9;
#pragma unroll
        for (int i = 0; i < 9; ++i) {
#pragma unroll
            for (int j = i; j < 9; ++j) acc[k++] += f[i] * f[j];
        }

        m = mn; v = vn; np = npn; cd = cdn;
    }

    // full-wave butterfly (64 lanes)
#pragma unroll
    for (int k = 0; k < 54; ++k) {
        float a = acc[k];
#pragma unroll
        for (int w = 32; w >= 1; w >>= 1) a += __shfl_xor(a, w);
        acc[k] = a;
    }
    __shared__ float red[B1 / 64][54];
    if ((tid & 63) == 0) {
#pragma unroll
        for (int k = 0; k < 54; ++k) red[tid >> 6][k] = acc[k];
    }
    __syncthreads();
    if (tid < 54) {
        float t = 0.f;
#pragma unroll
        for (int wv = 0; wv < B1 / 64; ++wv) t += red[wv][tid];
        partials[tid * G1 + blockIdx.x] = t;   // transposed: [k][block]
    }
}

// ---------------------------------------------------------------------------
// Finalize: parallel reduce of [54][G1] partials (4 threads per stat, each a
// contiguous G1/4 run), then per-channel scale/bias.
// ---------------------------------------------------------------------------
__global__ __launch_bounds__(256) void pfn_finalize(
    const float* __restrict__ partials, const float* __restrict__ W,
    const float* __restrict__ gamma, const float* __restrict__ beta,
    float* __restrict__ sb, float invN)
{
    const int t = threadIdx.x;
    __shared__ float red[54][4];
    __shared__ float tot[54];

    if (t < 216) {
        const int k = t >> 2, q = t & 3;
        const float* p = partials + k * G1 + q * (G1 / 4);
        float s = 0.f;
#pragma unroll 16
        for (int i = 0; i < G1 / 4; ++i) s += p[i];
        red[k][q] = s;
    }
    __syncthreads();
    if (t < 54) tot[t] = red[t][0] + red[t][1] + red[t][2] + red[t][3];
    __syncthreads();

    if (t < 64) {
        float w[9];
#pragma unroll
        for (int c = 0; c < 9; ++c) w[c] = W[c * OUTC + t];

        float mean = 0.f;
#pragma unroll
        for (int c = 0; c < 9; ++c) mean += (tot[c] * invN) * w[c];

        float ex2 = 0.f;
        int k = 9;
#pragma unroll
        for (int i = 0; i < 9; ++i) {
#pragma unroll
            for (int j = i; j < 9; ++j) {
                const float q = tot[k++] * invN;
                ex2 += ((i == j) ? 1.f : 2.f) * q * w[i] * w[j];
            }
        }
        const float var = ex2 - mean * mean;
        const float sc  = gamma[t] * rsqrtf(var + BNEPS);
        sb[t]      = sc;
        sb[64 + t] = beta[t] - mean * sc;
    }
}

// ---------------------------------------------------------------------------
// Pass 2: LDS double-buffered. Block = 256 threads, PPB=32 pillars, chunks of
// CH=8 pillars staged via global_load_lds (16B/lane, coalesced). Each wave
// computes 2 pillars/chunk from broadcast LDS reads; 4 independent max chains.
// ---------------------------------------------------------------------------
__global__ __launch_bounds__(256) void pfn_out(
    const float* __restrict__ vox, const int4* __restrict__ coords,
    const float4* __restrict__ means, const float* __restrict__ sb,
    const float* __restrict__ W, float* __restrict__ out, int M)
{
    __shared__ float4 sbuf[2][CH][PP];
    const int tid  = threadIdx.x;
    const int o    = tid & 63;          // output channel
    const int lane = tid & 63;
    const int wv   = tid >> 6;          // wave id (0..3)
    const int m0   = blockIdx.x * PPB;
    if (m0 >= M) return;

    const float s  = sb[o];
    const float bb = sb[64 + o];
    float wr[9];
#pragma unroll
    for (int c = 0; c < 9; ++c) wr[c] = W[c * OUTC + o];
    const float As = s * (wr[0] + wr[4] + wr[7]);
    const float Bs = s * (wr[1] + wr[5] + wr[8]);
    const float Cs = s * (wr[2] + wr[6]);
    const float Ds = s * wr[3];
    const float s4 = s * wr[4], s5 = s * wr[5], s6 = s * wr[6];
    const float s7 = s * wr[7], s8 = s * wr[8];

    const int npil = (M - m0 < PPB) ? (M - m0) : PPB;
    const int nch  = (npil + CH - 1) / CH;

    // stage chunk 0
    {
        const int pm  = m0 + wv * 2;
        const int pil = pm + (lane >> 5);
        if (pil < M) {
            const float* g = vox + (size_t)pil * PP * 4 + (size_t)(lane & 31) * 4;
            __builtin_amdgcn_global_load_lds(
                (const __attribute__((address_space(1))) void*)g,
                (__attribute__((address_space(3))) void*)&sbuf[0][wv * 2][0],
                16, 0, 0);
        }
    }

    for (int c = 0; c < nch; ++c) {
        __syncthreads();                       // chunk c resident in sbuf[c&1]
        if (c + 1 < nch) {                     // stage next chunk under compute
            const int pm  = m0 + (c + 1) * CH + wv * 2;
            const int pil = pm + (lane >> 5);
            if (pil < M) {
                const float* g = vox + (size_t)pil * PP * 4 + (size_t)(lane & 31) * 4;
                __builtin_amdgcn_global_load_lds(
                    (const __attribute__((address_space(1))) void*)g,
                    (__attribute__((address_space(3))) void*)&sbuf[(c + 1) & 1][wv * 2][0],
                    16, 0, 0);
            }
        }

        const int pA = m0 + c * CH + wv * 2;
        const int pB = pA + 1;
        float EA = 0.f, EB = 0.f;
        if (pA < M) {
            const float4 mA = means[pA];
            const int4   cA = coords[pA];
            EA = bb - (mA.x * s4 + mA.y * s5 + mA.z * s6 +
                       ((float)cA.w * VX + X0) * s7 + ((float)cA.z * VY + Y0) * s8);
        }
        if (pB < M) {
            const float4 mB = means[pB];
            const int4   cB = coords[pB];
            EB = bb - (mB.x * s4 + mB.y * s5 + mB.z * s6 +
                       ((float)cB.w * VX + X0) * s7 + ((float)cB.z * VY + Y0) * s8);
        }

        const float4* bA = &sbuf[c & 1][wv * 2][0];
        const float4* bB = &sbuf[c & 1][wv * 2 + 1][0];
        float gA0 = -INFINITY, gA1 = -INFINITY;
        float gB0 = -INFINITY, gB1 = -INFINITY;
#pragma unroll
        for (int p = 0; p < PP; p += 2) {
            const float4 a0 = bA[p], a1 = bA[p + 1];
            const float4 b0 = bB[p], b1 = bB[p + 1];
            float h;
            h = a0.x * As; h = fmaf(a0.y, Bs, h); h = fmaf(a0.z, Cs, h);
            h = fmaf(a0.w, Ds, h); gA0 = fmaxf(gA0, h);
            h = a1.x * As; h = fmaf(a1.y, Bs, h); h = fmaf(a1.z, Cs, h);
            h = fmaf(a1.w, Ds, h); gA1 = fmaxf(gA1, h);
            h = b0.x * As; h = fmaf(b0.y, Bs, h); h = fmaf(b0.z, Cs, h);
            h = fmaf(b0.w, Ds, h); gB0 = fmaxf(gB0, h);
            h = b1.x * As; h = fmaf(b1.y, Bs, h); h = fmaf(b1.z, Cs, h);
            h = fmaf(b1.w, Ds, h); gB1 = fmaxf(gB1, h);
        }
        if (pA < M) out[(size_t)pA * OUTC + o] = fmaxf(fmaxf(gA0, gA1) + EA, 0.f);
        if (pB < M) out[(size_t)pB * OUTC + o] = fmaxf(fmaxf(gB0, gB1) + EB, 0.f);
    }
}

// ---------------------------------------------------------------------------
extern "C" void kernel_launch(void* const* d_in, const int* in_sizes, int n_in,
                              void* d_out, int out_size, void* d_ws, size_t ws_size,
                              hipStream_t stream)
{
    const float* voxels = (const float*)d_in[0];
    const int*   coords = (const int*)d_in[1];
    const int*   npts   = (const int*)d_in[2];
    const float* W      = (const float*)d_in[3];
    const float* gamma  = (const float*)d_in[4];
    const float* beta   = (const float*)d_in[5];
    float*       out    = (float*)d_out;

    const int M = in_sizes[0] / (PP * 4);     // voxels is (M, P, 4)

    // ws layout (floats): partials[54*G1] | sb[128] | means4[4*M]
    float*  ws       = (float*)d_ws;
    float*  partials = ws;
    float*  sb       = ws + 54 * G1;
    float4* means4   = (float4*)(ws + 54 * G1 + 128);   // byte offset 111104, 16B-aligned

    const int grid3 = (M + PPB - 1) / PPB;

    pfn_stats<<<G1, B1, 0, stream>>>((const float4*)voxels, (const int4*)coords,
                                     npts, partials, means4, M);
    pfn_finalize<<<1, 256, 0, stream>>>(partials, W, gamma, beta, sb,
                                        1.f / (float)(M * PP));
    pfn_out<<<grid3, 256, 0, stream>>>(voxels, (const int4*)coords, means4, sb,
                                       W, out, M);
}

// Round 5
// 114.777 us; speedup vs baseline: 1.4106x; 1.1037x over previous
//
#include <hip/hip_runtime.h>
#include <math.h>

// PillarFeatureNet fused: augment(9) -> linear(9x64) -> BN(train, global
// stats) -> ReLU -> max over P.
//
// Algebra:
//  h[m,p,o] = x(W0+W4+W7) + y(W1+W5+W8) + z(W2+W6) + r*W3
//             - (mx*W4 + my*W5 + mz*W6 + px*W7 + py*W8)
//           = dot(v_p, ABCD_o) + E0[m][o]            (E0 point-independent)
//  BN: mean_o / var_o from 9-vec first + 9x9 second feature moments.
//  s_o = gamma*rsqrt(var+eps) > 0 (gamma=1), so
//  out = relu(max_p(s*h+b)) = relu(s*(max_p dot + E0) + b) = relu(s*R + b)
//  where R[m][o] = max_p dot(v_p, ABCD_o) + E0[m][o] is BN-INDEPENDENT.
//  => K1 computes R + moments in ONE pass over voxels; K3 is elementwise.

#define PP   32
#define OUTC 64
#define G1   512     // K1 grid (also partials width)
#define B1   256     // K1 block: 4 waves, 1 pillar-pair per wave per iter

static constexpr float VX = 0.2f, VY = 0.2f;
static constexpr float X0 = -51.2f, Y0 = -51.2f;
static constexpr float BNEPS = 1e-3f;

// ---------------------------------------------------------------------------
// K1: per wave, iterate pillar PAIRS (depth-1 prefetch).
//   Phase M (lane = pillar-half * 32 + point): mean via 32-lane xor-reduce,
//     accumulate 9+45 feature moments per lane.
//   Phase R (lane = output channel): walk the pair's 64 points via
//     wave-uniform scalar loads; 4 FMA + max per point; fold E0; write R.
// No LDS staging, no __syncthreads in the main loop.
// ---------------------------------------------------------------------------
__global__ __launch_bounds__(B1) void pfn_main(
    const float4* __restrict__ vox, const int4* __restrict__ coords,
    const int* __restrict__ npts, const float* __restrict__ W,
    float* __restrict__ partials, float* __restrict__ R, int M)
{
    const int tid  = threadIdx.x;
    const int lane = tid & 63;
    const int wv   = tid >> 6;
    const int q    = lane & 31;       // point index within half
    const int hf   = lane >> 5;       // 0 = pillar A, 1 = pillar B

    // per-lane channel weights (lane = o)
    float w[9];
#pragma unroll
    for (int c = 0; c < 9; ++c) w[c] = W[c * OUTC + lane];
    const float Ac = w[0] + w[4] + w[7];
    const float Bc = w[1] + w[5] + w[8];
    const float Cc = w[2] + w[6];
    const float Dc = w[3];

    float acc[54];
#pragma unroll
    for (int k = 0; k < 54; ++k) acc[k] = 0.f;

    const int pairs = M >> 1;         // M is even (40000)
    const int pstr  = G1 * (B1 / 64);

    int pr = blockIdx.x * (B1 / 64) + wv;
    float4 v  = make_float4(0.f, 0.f, 0.f, 0.f);
    int    np = 1;
    int4   cd = make_int4(0, 0, 0, 0);
    if (pr < pairs) {
        const int p = pr * 2 + hf;
        v = vox[(size_t)p * PP + q];
        np = npts[p];
        cd = coords[p];
    }

    while (pr < pairs) {
        // ---- prefetch next pair ----
        const int prn = pr + pstr;
        float4 vn  = make_float4(0.f, 0.f, 0.f, 0.f);
        int    npn = 1;
        int4   cdn = make_int4(0, 0, 0, 0);
        if (prn < pairs) {
            const int p = prn * 2 + hf;
            vn = vox[(size_t)p * PP + q];
            npn = npts[p];
            cdn = coords[p];
        }

        // ---- phase M: mean + moments (lane = half*32 + point) ----
        float sx = v.x, sy = v.y, sz = v.z;
#pragma unroll
        for (int msk = 16; msk >= 1; msk >>= 1) {
            sx += __shfl_xor(sx, msk);
            sy += __shfl_xor(sy, msk);
            sz += __shfl_xor(sz, msk);
        }
        if (np < 1) np = 1;
        const float inv = 1.f / (float)np;
        const float mx = sx * inv, my = sy * inv, mz = sz * inv;
        const float px = (float)cd.w * VX + X0;
        const float py = (float)cd.z * VY + Y0;

        {
            float f[9];
            f[0] = v.x; f[1] = v.y; f[2] = v.z; f[3] = v.w;
            f[4] = v.x - mx; f[5] = v.y - my; f[6] = v.z - mz;
            f[7] = v.x - px; f[8] = v.y - py;
#pragma unroll
            for (int i = 0; i < 9; ++i) acc[i] += f[i];
            int k = 9;
#pragma unroll
            for (int i = 0; i < 9; ++i) {
#pragma unroll
                for (int j = i; j < 9; ++j) acc[k++] += f[i] * f[j];
            }
        }

        // ---- phase R: lane = channel; pillar data via scalar loads ----
        const int pA  = pr * 2;
        const int pAu = __builtin_amdgcn_readfirstlane(pA);
        const float4* __restrict__ sp = vox + (size_t)pAu * PP;  // A then B

        float gA0 = -INFINITY, gA1 = -INFINITY, gA2 = -INFINITY, gA3 = -INFINITY;
        float gB0 = -INFINITY, gB1 = -INFINITY, gB2 = -INFINITY, gB3 = -INFINITY;
#pragma unroll
        for (int pt = 0; pt < PP; pt += 4) {
            const float4 a0 = sp[pt],     a1 = sp[pt + 1];
            const float4 a2 = sp[pt + 2], a3 = sp[pt + 3];
            float h;
            h = fmaf(a0.x, Ac, fmaf(a0.y, Bc, fmaf(a0.z, Cc, a0.w * Dc)));
            gA0 = fmaxf(gA0, h);
            h = fmaf(a1.x, Ac, fmaf(a1.y, Bc, fmaf(a1.z, Cc, a1.w * Dc)));
            gA1 = fmaxf(gA1, h);
            h = fmaf(a2.x, Ac, fmaf(a2.y, Bc, fmaf(a2.z, Cc, a2.w * Dc)));
            gA2 = fmaxf(gA2, h);
            h = fmaf(a3.x, Ac, fmaf(a3.y, Bc, fmaf(a3.z, Cc, a3.w * Dc)));
            gA3 = fmaxf(gA3, h);
        }
#pragma unroll
        for (int pt = 0; pt < PP; pt += 4) {
            const float4 b0 = sp[PP + pt],     b1 = sp[PP + pt + 1];
            const float4 b2 = sp[PP + pt + 2], b3 = sp[PP + pt + 3];
            float h;
            h = fmaf(b0.x, Ac, fmaf(b0.y, Bc, fmaf(b0.z, Cc, b0.w * Dc)));
            gB0 = fmaxf(gB0, h);
            h = fmaf(b1.x, Ac, fmaf(b1.y, Bc, fmaf(b1.z, Cc, b1.w * Dc)));
            gB1 = fmaxf(gB1, h);
            h = fmaf(b2.x, Ac, fmaf(b2.y, Bc, fmaf(b2.z, Cc, b2.w * Dc)));
            gB2 = fmaxf(gB2, h);
            h = fmaf(b3.x, Ac, fmaf(b3.y, Bc, fmaf(b3.z, Cc, b3.w * Dc)));
            gB3 = fmaxf(gB3, h);
        }

        // broadcast per-pillar scalars to all 64 lanes
        const float mxA = __shfl(mx, 0),  myA = __shfl(my, 0),  mzA = __shfl(mz, 0);
        const float pxA = __shfl(px, 0),  pyA = __shfl(py, 0);
        const float mxB = __shfl(mx, 32), myB = __shfl(my, 32), mzB = __shfl(mz, 32);
        const float pxB = __shfl(px, 32), pyB = __shfl(py, 32);

        const float E0A = -(mxA * w[4] + myA * w[5] + mzA * w[6] +
                            pxA * w[7] + pyA * w[8]);
        const float E0B = -(mxB * w[4] + myB * w[5] + mzB * w[6] +
                            pxB * w[7] + pyB * w[8]);

        const float RA = fmaxf(fmaxf(gA0, gA1), fmaxf(gA2, gA3)) + E0A;
        const float RB = fmaxf(fmaxf(gB0, gB1), fmaxf(gB2, gB3)) + E0B;
        R[(size_t)pA * OUTC + lane]       = RA;
        R[(size_t)(pA + 1) * OUTC + lane] = RB;

        pr = prn; v = vn; np = npn; cd = cdn;
    }

    // ---- moment reduction: 64-lane butterfly, cross-wave via LDS ----
#pragma unroll
    for (int k = 0; k < 54; ++k) {
        float a = acc[k];
#pragma unroll
        for (int msk = 32; msk >= 1; msk >>= 1) a += __shfl_xor(a, msk);
        acc[k] = a;
    }
    __shared__ float red[B1 / 64][54];
    if (lane == 0) {
#pragma unroll
        for (int k = 0; k < 54; ++k) red[wv][k] = acc[k];
    }
    __syncthreads();
    if (tid < 54) {
        float t = 0.f;
#pragma unroll
        for (int u = 0; u < B1 / 64; ++u) t += red[u][tid];
        partials[tid * G1 + blockIdx.x] = t;   // transposed [k][block]
    }
}

// ---------------------------------------------------------------------------
// K2: reduce [54][G1] partials (4 threads/stat, contiguous runs), then
// per-channel scale/bias.
// ---------------------------------------------------------------------------
__global__ __launch_bounds__(256) void pfn_finalize(
    const float* __restrict__ partials, const float* __restrict__ W,
    const float* __restrict__ gamma, const float* __restrict__ beta,
    float* __restrict__ sb, float invN)
{
    const int t = threadIdx.x;
    __shared__ float red[54][4];
    __shared__ float tot[54];

    if (t < 216) {
        const int k = t >> 2, qq = t & 3;
        const float* p = partials + k * G1 + qq * (G1 / 4);
        float s = 0.f;
#pragma unroll 16
        for (int i = 0; i < G1 / 4; ++i) s += p[i];
        red[k][qq] = s;
    }
    __syncthreads();
    if (t < 54) tot[t] = red[t][0] + red[t][1] + red[t][2] + red[t][3];
    __syncthreads();

    if (t < 64) {
        float w[9];
#pragma unroll
        for (int c = 0; c < 9; ++c) w[c] = W[c * OUTC + t];

        float mean = 0.f;
#pragma unroll
        for (int c = 0; c < 9; ++c) mean += (tot[c] * invN) * w[c];

        float ex2 = 0.f;
        int k = 9;
#pragma unroll
        for (int i = 0; i < 9; ++i) {
#pragma unroll
            for (int j = i; j < 9; ++j) {
                const float qv = tot[k++] * invN;
                ex2 += ((i == j) ? 1.f : 2.f) * qv * w[i] * w[j];
            }
        }
        const float var = ex2 - mean * mean;
        const float sc  = gamma[t] * rsqrtf(var + BNEPS);
        sb[t]      = sc;
        sb[64 + t] = beta[t] - mean * sc;
    }
}

// ---------------------------------------------------------------------------
// K3: out = relu(s * R + b), pure elementwise (float4), fully coalesced.
// ---------------------------------------------------------------------------
__global__ __launch_bounds__(256) void pfn_apply(
    const float4* __restrict__ R4, const float* __restrict__ sb,
    float4* __restrict__ out4, int n4)
{
    const int i = blockIdx.x * 256 + threadIdx.x;
    if (i >= n4) return;
    const int og = i & (OUTC / 4 - 1);                 // float4 group in channel dim
    const float4 r = R4[i];
    const float4 s = reinterpret_cast<const float4*>(sb)[og];
    const float4 b = reinterpret_cast<const float4*>(sb + OUTC)[og];
    float4 o;
    o.x = fmaxf(fmaf(s.x, r.x, b.x), 0.f);
    o.y = fmaxf(fmaf(s.y, r.y, b.y), 0.f);
    o.z = fmaxf(fmaf(s.z, r.z, b.z), 0.f);
    o.w = fmaxf(fmaf(s.w, r.w, b.w), 0.f);
    out4[i] = o;
}

// ---------------------------------------------------------------------------
extern "C" void kernel_launch(void* const* d_in, const int* in_sizes, int n_in,
                              void* d_out, int out_size, void* d_ws, size_t ws_size,
                              hipStream_t stream)
{
    const float* voxels = (const float*)d_in[0];
    const int*   coords = (const int*)d_in[1];
    const int*   npts   = (const int*)d_in[2];
    const float* W      = (const float*)d_in[3];
    const float* gamma  = (const float*)d_in[4];
    const float* beta   = (const float*)d_in[5];
    float*       out    = (float*)d_out;

    const int M = in_sizes[0] / (PP * 4);     // voxels is (M, P, 4); M even here

    // ws layout (floats): partials[54*G1] | sb[128] | R[M*64]
    float* ws       = (float*)d_ws;
    float* partials = ws;
    float* sb       = ws + 54 * G1;
    float* R        = sb + 128;               // byte offset 111104, 16B aligned

    pfn_main<<<G1, B1, 0, stream>>>((const float4*)voxels, (const int4*)coords,
                                    npts, W, partials, R, M);
    pfn_finalize<<<1, 256, 0, stream>>>(partials, W, gamma, beta, sb,
                                        1.f / (float)(M * PP));
    const int n4 = M * (OUTC / 4);
    pfn_apply<<<(n4 + 255) / 256, 256, 0, stream>>>((const float4*)R, sb,
                                                    (float4*)out, n4);
}